// Round 9
// baseline (1225.350 us; speedup 1.0000x reference)
//
#include <hip/hip_runtime.h>

#define N_ROWS 32768
#define DIM    512
#define K_CODES 8192
#define BM 256
#define BN 256
#define BK 64
#define NB (K_CODES / BN)   /* 32 code tiles */
#define MARGIN 3e-3f

typedef short s16x8 __attribute__((ext_vector_type(8)));
typedef float f32x4 __attribute__((ext_vector_type(4)));
typedef unsigned long long u64;

__device__ __forceinline__ unsigned short f2bf(float f) {
  unsigned int u = __float_as_uint(f);
  u = (u + 0x7fffu + ((u >> 16) & 1u)) >> 16;   // RNE
  return (unsigned short)u;
}

// order-preserving float->u32 (monotonic unsigned compare)
__device__ __forceinline__ unsigned int ordf(float f) {
  unsigned int u = __float_as_uint(f);
  return (u & 0x80000000u) ? ~u : (u | 0x80000000u);
}
__device__ __forceinline__ float unordf(unsigned int o) {
  return (o & 0x80000000u) ? __uint_as_float(o ^ 0x80000000u) : __uint_as_float(~o);
}

__device__ __forceinline__ void gload_lds16(const void* g, void* l) {
  __builtin_amdgcn_global_load_lds(
      (const __attribute__((address_space(1))) void*)g,
      (__attribute__((address_space(3))) void*)l,
      16, 0, 0);
}

// merge ordered pair (e1 >= e2) into running top-2 keys
__device__ __forceinline__ void kmerge(u64& K1, u64& K2, u64 e1, u64 e2) {
  if (e1 > K1) { K2 = (K1 > e2) ? K1 : e2; K1 = e1; }
  else if (e1 > K2) { K2 = e1; }
}

// ---- unified normalize: blocks [0,2048) -> W rows, [2048,10240) -> X rows ----
__global__ void prep_all(const float* __restrict__ W, const float* __restrict__ X,
                         unsigned short* __restrict__ wn16, unsigned short* __restrict__ xn16,
                         float* __restrict__ wnorm, float* __restrict__ wn2,
                         float* __restrict__ xnorm) {
  int b = blockIdx.x;
  bool isW = b < (K_CODES / 4);
  int row = (isW ? b : b - K_CODES / 4) * 4 + (threadIdx.x >> 6);
  int l = threadIdx.x & 63;
  const float* src = isW ? W : X;
  const float4* p = (const float4*)&src[(size_t)row * DIM + l * 8];
  float4 v0 = p[0], v1 = p[1];
  float ss = v0.x * v0.x + v0.y * v0.y + v0.z * v0.z + v0.w * v0.w
           + v1.x * v1.x + v1.y * v1.y + v1.z * v1.z + v1.w * v1.w;
#pragma unroll
  for (int o = 32; o; o >>= 1) ss += __shfl_xor(ss, o);
  float nrm = fmaxf(sqrtf(ss), 1e-12f);
  float q[8];
  q[0] = v0.x / nrm; q[1] = v0.y / nrm; q[2] = v0.z / nrm; q[3] = v0.w / nrm;
  q[4] = v1.x / nrm; q[5] = v1.y / nrm; q[6] = v1.z / nrm; q[7] = v1.w / nrm;
  s16x8 bv;
#pragma unroll
  for (int j = 0; j < 8; j++) bv[j] = (short)f2bf(q[j]);
  unsigned short* dst = isW ? wn16 : xn16;
  *(s16x8*)&dst[(size_t)row * DIM + l * 8] = bv;
  if (isW) {
    float s2 = q[0]*q[0] + q[1]*q[1] + q[2]*q[2] + q[3]*q[3]
             + q[4]*q[4] + q[5]*q[5] + q[6]*q[6] + q[7]*q[7];
#pragma unroll
    for (int o = 32; o; o >>= 1) s2 += __shfl_xor(s2, o);
    if (l == 0) { wnorm[row] = nrm; wn2[row] = s2; }
  } else {
    if (l == 0) xnorm[row] = nrm;
  }
}

// ---- 256x256 8-wave bf16 MFMA GEMM + fused in-register/LDS top-2 ----
__global__ __launch_bounds__(512, 2) void gemm_top2(
    const unsigned short* __restrict__ xn16, const unsigned short* __restrict__ wn16,
    float* __restrict__ pv, int* __restrict__ pi) {
  union SMem {
    struct { unsigned short A[BM * BK]; unsigned short B[BN * BK]; } st;  // 64 KB
    uint4 ep[64 * 65];                                                    // 65 KB
  };
  __shared__ SMem sm;
  // XCD-aware swizzle: 4096 blocks, each XCD owns 4 bx columns x all 128 by
  int wg = blockIdx.x;
  int virt = (wg & 7) * 512 + (wg >> 3);
  int bx = virt >> 7;               // 0..31
  int by = virt & 127;              // 0..127
  int t = threadIdx.x;
  int w = t >> 6, l = t & 63;
  int wr = w >> 2, wc = w & 3;      // wave grid: 2M x 4N; wave tile 128x64
  int rr = l & 15, hi = l >> 4;
  f32x4 acc[8][4] = {};

  // staging: chunk c = i*512+t; row c>>3, slot c&7, src slot XOR (row&7) (i-invariant)
  int srow = t >> 3;
  int sg = (t & 7) ^ (srow & 7);
  const unsigned short* aP = xn16 + (size_t)by * BM * DIM + (size_t)srow * DIM + sg * 8;
  const unsigned short* bP = wn16 + (size_t)bx * BN * DIM + (size_t)srow * DIM + sg * 8;

  // LDS fragment bases; row&7 == rr&7 (wr*128, wc*64, m*16 all mult of 8); ks=1 = base^32
  int aB0 = (wr * 128 + rr) * BK + ((hi ^ (rr & 7)) * 8);
  int bB0 = (wc * 64 + rr) * BK + ((hi ^ (rr & 7)) * 8);

  for (int k0 = 0; k0 < DIM; k0 += BK) {
#pragma unroll
    for (int i = 0; i < 4; i++) {
      gload_lds16(aP + (size_t)i * 64 * DIM, &sm.st.A[(i * 512 + t) * 8]);
      gload_lds16(bP + (size_t)i * 64 * DIM, &sm.st.B[(i * 512 + t) * 8]);
    }
    aP += BK; bP += BK;
    __syncthreads();                // drains vmcnt before LDS reads

    s16x8 aF[8], bF[4];
#pragma unroll
    for (int ks = 0; ks < 2; ks++) {
      int x = ks * 32;
#pragma unroll
      for (int m = 0; m < 8; m++) aF[m] = *(const s16x8*)&sm.st.A[(aB0 + m * 1024) ^ x];
#pragma unroll
      for (int n = 0; n < 4; n++) bF[n] = *(const s16x8*)&sm.st.B[(bB0 + n * 1024) ^ x];
#pragma unroll
      for (int m = 0; m < 8; m++)
#pragma unroll
        for (int n = 0; n < 4; n++)
          acc[m][n] = __builtin_amdgcn_mfma_f32_16x16x32_bf16(aF[m], bF[n], acc[m][n], 0, 0, 0);
    }
    __syncthreads();
  }

  // ======== epilogue: 4 passes of 64 rows; per-lane top2-of-4(n) -> ep -> merge ====
  // C/D: acc[m][n][r] -> row wr*128+m*16+hi*4+r, col wc*64+n*16+rr
  int wcbase = wc * 64;
#pragma unroll
  for (int P = 0; P < 4; P++) {
    if (wr == (P >> 1)) {
      const int mlo = (P & 1) * 4;
#pragma unroll
      for (int mm = 0; mm < 4; mm++) {
#pragma unroll
        for (int r = 0; r < 4; r++) {
          float v0 = acc[mlo + mm][0][r], v1 = acc[mlo + mm][1][r];
          float v2 = acc[mlo + mm][2][r], v3 = acc[mlo + mm][3][r];
          float a1, a2, d1, d2, t1, t2; int i1, i2, j1, j2, u1, u2;
          if (v1 > v0) { a1 = v1; i1 = 1; a2 = v0; i2 = 0; } else { a1 = v0; i1 = 0; a2 = v1; i2 = 1; }
          if (v3 > v2) { d1 = v3; j1 = 3; d2 = v2; j2 = 2; } else { d1 = v2; j1 = 2; d2 = v3; j2 = 3; }
          if (a1 >= d1) { t1 = a1; u1 = i1; if (d1 > a2) { t2 = d1; u2 = j1; } else { t2 = a2; u2 = i2; } }
          else          { t1 = d1; u1 = j1; if (a1 >= d2) { t2 = a1; u2 = i1; } else { t2 = d2; u2 = j2; } }
          int col1 = wcbase + u1 * 16 + rr, col2 = wcbase + u2 * 16 + rr;
          u64 k1 = ((u64)ordf(t1) << 32) | (unsigned)(~col1);
          u64 k2 = ((u64)ordf(t2) << 32) | (unsigned)(~col2);
          int row64 = mm * 16 + hi * 4 + r;
          sm.ep[row64 * 65 + wc * 16 + rr] =
              make_uint4((unsigned)k1, (unsigned)(k1 >> 32), (unsigned)k2, (unsigned)(k2 >> 32));
        }
      }
    }
    __syncthreads();
    if (t < 128) {
      int row64 = t >> 1, seg = t & 1;
      u64 K1 = 0, K2 = 0;
      for (int j = 0; j < 32; j++) {
        uint4 q = sm.ep[row64 * 65 + seg * 32 + j];
        u64 e1 = ((u64)q.y << 32) | q.x;
        u64 e2 = ((u64)q.w << 32) | q.z;
        kmerge(K1, K2, e1, e2);
      }
      // merge with partner (t^1, same wave): shuffle halves
      unsigned o1l = __shfl_xor((unsigned)K1, 1), o1h = __shfl_xor((unsigned)(K1 >> 32), 1);
      unsigned o2l = __shfl_xor((unsigned)K2, 1), o2h = __shfl_xor((unsigned)(K2 >> 32), 1);
      kmerge(K1, K2, ((u64)o1h << 32) | o1l, ((u64)o2h << 32) | o2l);
      if (seg == 0) {
        size_t rowg = (size_t)by * BM + P * 64 + row64;
        pv[(size_t)(bx * 2 + 0) * N_ROWS + rowg] = unordf((unsigned)(K1 >> 32));
        pv[(size_t)(bx * 2 + 1) * N_ROWS + rowg] = unordf((unsigned)(K2 >> 32));
        pi[(size_t)(bx * 2 + 0) * N_ROWS + rowg] = bx * BN + (int)(~(unsigned)K1);
        pi[(size_t)(bx * 2 + 1) * N_ROWS + rowg] = bx * BN + (int)(~(unsigned)K2);
      }
    }
    __syncthreads();
  }
}

// ---- collapse: per-row max over 64 entries + candidate list (argmax first) ----
__global__ void collapse(const float* __restrict__ pv, const int* __restrict__ pi,
                         int* __restrict__ cand) {
  int r = blockIdx.x * 256 + threadIdx.x;
  float mx = -1e30f; int be = 0;
#pragma unroll 8
  for (int e = 0; e < 2 * NB; e++) {
    float v = pv[(size_t)e * N_ROWS + r];
    if (v > mx) { mx = v; be = e; }
  }
  float thr = mx - MARGIN;
  cand[r * 8 + 1] = pi[(size_t)be * N_ROWS + r];
  int cnt = 1;
  for (int e = 0; e < 2 * NB; e++) {
    if (e == be) continue;
    float v = pv[(size_t)e * N_ROWS + r];
    if (v >= thr && cnt < 7) { cand[r * 8 + 1 + cnt] = pi[(size_t)e * N_ROWS + r]; cnt++; }
  }
  cand[r * 8] = cnt;
}

// ---- wave-per-row: rescore candidates fp32, emit quantized_st + partial loss ----
__global__ void reduce_rescore(
    const float* __restrict__ X, const float* __restrict__ W,
    const float* __restrict__ xnorm, const float* __restrict__ wnorm,
    const float* __restrict__ wn2, const int* __restrict__ cand,
    float* __restrict__ out, float* __restrict__ partial, float* __restrict__ outIdx) {
  int row = blockIdx.x * 4 + (threadIdx.x >> 6);
  int l = threadIdx.x & 63;

  float xnrm = xnorm[row];
  const float4* xp = (const float4*)&X[(size_t)row * DIM + l * 8];
  float4 a0 = xp[0], a1 = xp[1];
  float xq[8];
  xq[0] = a0.x / xnrm; xq[1] = a0.y / xnrm; xq[2] = a0.z / xnrm; xq[3] = a0.w / xnrm;
  xq[4] = a1.x / xnrm; xq[5] = a1.y / xnrm; xq[6] = a1.z / xnrm; xq[7] = a1.w / xnrm;

  int cnt = cand[row * 8];
  float bestDist = 1e30f; int bestIdx = 0x7fffffff;
  for (int ci = 0; ci < cnt; ci++) {
    int c = cand[row * 8 + 1 + ci];
    float wnr = wnorm[c];
    const float4* wp = (const float4*)&W[(size_t)c * DIM + l * 8];
    float4 w0 = wp[0], w1 = wp[1];
    float d = xq[0] * (w0.x / wnr) + xq[1] * (w0.y / wnr)
            + xq[2] * (w0.z / wnr) + xq[3] * (w0.w / wnr)
            + xq[4] * (w1.x / wnr) + xq[5] * (w1.y / wnr)
            + xq[6] * (w1.z / wnr) + xq[7] * (w1.w / wnr);
#pragma unroll
    for (int o = 32; o; o >>= 1) d += __shfl_xor(d, o);
    float dist = wn2[c] - 2.0f * d;
    if (dist < bestDist || (dist == bestDist && c < bestIdx)) { bestDist = dist; bestIdx = c; }
  }

  int c = bestIdx;
  float wnr = wnorm[c];
  const float4* wp = (const float4*)&W[(size_t)c * DIM + l * 8];
  float4 w0 = wp[0], w1 = wp[1];
  float q[8];
  q[0] = w0.x / wnr; q[1] = w0.y / wnr; q[2] = w0.z / wnr; q[3] = w0.w / wnr;
  q[4] = w1.x / wnr; q[5] = w1.y / wnr; q[6] = w1.z / wnr; q[7] = w1.w / wnr;
  float4 o0, o1;
  o0.x = xq[0] + (q[0] - xq[0]); o0.y = xq[1] + (q[1] - xq[1]);
  o0.z = xq[2] + (q[2] - xq[2]); o0.w = xq[3] + (q[3] - xq[3]);
  o1.x = xq[4] + (q[4] - xq[4]); o1.y = xq[5] + (q[5] - xq[5]);
  o1.z = xq[6] + (q[6] - xq[6]); o1.w = xq[7] + (q[7] - xq[7]);
  float4* op = (float4*)&out[(size_t)row * DIM + l * 8];
  op[0] = o0; op[1] = o1;
  float ssum = 0.f;
#pragma unroll
  for (int j = 0; j < 8; j++) { float df = q[j] - xq[j]; ssum += df * df; }
#pragma unroll
  for (int o = 32; o; o >>= 1) ssum += __shfl_xor(ssum, o);
  if (l == 0) { partial[row] = ssum; outIdx[row] = (float)c; }
}

// ---- loss reduction: wave-reduce + atomic ----
__global__ void reduce_loss(const float* __restrict__ partial, float* __restrict__ accum) {
  int i = blockIdx.x * 256 + threadIdx.x;
  float s = partial[i];
#pragma unroll
  for (int o = 32; o; o >>= 1) s += __shfl_xor(s, o);
  if ((threadIdx.x & 63) == 0) atomicAdd(accum, s);
}

__global__ void write_loss(const float* __restrict__ accum, float* __restrict__ out) {
  out[0] = (float)(1.25 * (double)accum[0] / (double)((size_t)N_ROWS * DIM));
}

extern "C" void kernel_launch(void* const* d_in, const int* in_sizes, int n_in,
                              void* d_out, int out_size, void* d_ws, size_t ws_size,
                              hipStream_t stream) {
  const float* x = (const float*)d_in[0];
  const float* W = (const float*)d_in[1];
  float* out = (float*)d_out;
  char* ws = (char*)d_ws;

  unsigned short* wn16 = (unsigned short*)(ws);                 //  8 MB
  unsigned short* xn16 = (unsigned short*)(ws + 8388608);       // 32 MB (dead after gemm)
  float* wnorm = (float*)(ws + 41943040);                       // 32 KB
  float* wn2   = (float*)(ws + 41975808);                       // 32 KB
  float* xnorm = (float*)(ws + 42008576);                       // 128 KB
  float* pv    = (float*)(ws + 42139648);                       // 8 MB used
  int*   pi    = (int*)  (ws + 58916864);                       // 8 MB used
  float* accum = (float*)(ws + 75694080);                       // 4 B
  // these reuse the dead xn16 region (only written after gemm_top2):
  float* partial = (float*)(ws + 8388608);                      // 128 KB
  int*   cand    = (int*)  (ws + 8519680);                      // 1 MB

  hipMemsetAsync(accum, 0, sizeof(float), stream);
  prep_all<<<K_CODES / 4 + N_ROWS / 4, 256, 0, stream>>>(W, x, wn16, xn16, wnorm, wn2, xnorm);
  gemm_top2<<<(K_CODES / BN) * (N_ROWS / BM), 512, 0, stream>>>(xn16, wn16, pv, pi);
  collapse<<<N_ROWS / 256, 256, 0, stream>>>(pv, pi, cand);
  reduce_rescore<<<N_ROWS / 4, 256, 0, stream>>>(
      x, W, xnorm, wnorm, wn2, cand, out, partial,
      out + (size_t)N_ROWS * DIM + 1);
  reduce_loss<<<N_ROWS / 256, 256, 0, stream>>>(partial, accum);
  write_loss<<<1, 1, 0, stream>>>(accum, out + (size_t)N_ROWS * DIM);
}